// Round 1
// baseline (420.838 us; speedup 1.0000x reference)
//
#include <hip/hip_runtime.h>
#include <hip/hip_bf16.h>
#include <stdint.h>

// ---------------------------------------------------------------------------
// CausalSelfAttention on MI355X: bf16 MFMA pipeline
//   cast -> fused QKV GEMM (m97 structure) -> RoPE(q*scale, k) -> V transpose
//        -> flash attention (64-row q tiles, swizzled LDS) -> out GEMM
// ---------------------------------------------------------------------------

typedef short bf16x8 __attribute__((ext_vector_type(8)));
typedef float f32x4  __attribute__((ext_vector_type(4)));

static __device__ __forceinline__ short f2bf(float f) {
  unsigned u = __builtin_bit_cast(unsigned, f);
  u = (u + 0x7fffu + ((u >> 16) & 1u)) >> 16;   // RNE
  return (short)u;
}
static __device__ __forceinline__ float bf2f(short s) {
  unsigned u = ((unsigned)(unsigned short)s) << 16;
  return __builtin_bit_cast(float, u);
}
static __device__ __forceinline__ void gload_lds16(const void* g, void* l) {
  auto gp = (const __attribute__((address_space(1))) void*)(g);
  auto lp = (__attribute__((address_space(3))) void*)(l);
  __builtin_amdgcn_global_load_lds(gp, lp, 16, 0, 0);
}

// ------------------------------ cast kernels -------------------------------
__global__ __launch_bounds__(256) void cast8_kernel(const float* __restrict__ in,
                                                    short* __restrict__ out, int n8) {
  int g = blockIdx.x * 256 + threadIdx.x;
  if (g >= n8) return;
  const float4* p = (const float4*)(in + (size_t)g * 8);
  float4 a = p[0], b = p[1];
  bf16x8 o;
  o[0] = f2bf(a.x); o[1] = f2bf(a.y); o[2] = f2bf(a.z); o[3] = f2bf(a.w);
  o[4] = f2bf(b.x); o[5] = f2bf(b.y); o[6] = f2bf(b.z); o[7] = f2bf(b.w);
  *(bf16x8*)(out + (size_t)g * 8) = o;
}

__global__ __launch_bounds__(256) void castw_kernel(const float* __restrict__ w0,
                                                    const float* __restrict__ w1,
                                                    const float* __restrict__ w2,
                                                    const float* __restrict__ w3,
                                                    short* __restrict__ out) {
  int seg = blockIdx.y;
  const float* in = (seg == 0) ? w0 : (seg == 1) ? w1 : (seg == 2) ? w2 : w3;
  short* o = out + (size_t)seg * 4194304;
  int g = blockIdx.x * 256 + threadIdx.x;     // < 524288 exactly
  const float4* p = (const float4*)(in + (size_t)g * 8);
  float4 a = p[0], b = p[1];
  bf16x8 v;
  v[0] = f2bf(a.x); v[1] = f2bf(a.y); v[2] = f2bf(a.z); v[3] = f2bf(a.w);
  v[4] = f2bf(b.x); v[5] = f2bf(b.y); v[6] = f2bf(b.z); v[7] = f2bf(b.w);
  *(bf16x8*)(o + (size_t)g * 8) = v;
}

// ------------------------------ RoPE (in place) ----------------------------
// layout (B,H,T,D) bf16; pairs adjacent in D; cos/sin (T, 64) f32
__global__ __launch_bounds__(256) void rope_kernel(short* __restrict__ qk,
                                                   const float* __restrict__ cs,
                                                   const float* __restrict__ sn,
                                                   float scale) {
  int g = blockIdx.x * 256 + threadIdx.x;     // < 1048576 exactly
  size_t e0 = (size_t)g * 8;
  int d0 = (int)(e0 & 127);
  int t  = (int)((e0 >> 7) & 2047);
  bf16x8 v = *(bf16x8*)(qk + e0);
  float4 c = *(const float4*)(cs + t * 64 + (d0 >> 1));
  float4 s = *(const float4*)(sn + t * 64 + (d0 >> 1));
  float cc[4] = {c.x, c.y, c.z, c.w};
  float ss[4] = {s.x, s.y, s.z, s.w};
  bf16x8 o;
#pragma unroll
  for (int i = 0; i < 4; ++i) {
    float x0 = bf2f(v[2 * i]), x1 = bf2f(v[2 * i + 1]);
    o[2 * i]     = f2bf((x0 * cc[i] - x1 * ss[i]) * scale);
    o[2 * i + 1] = f2bf((x0 * ss[i] + x1 * cc[i]) * scale);
  }
  *(bf16x8*)(qk + e0) = o;
}

// ------------------------- V transpose (BHTD -> BHDT) ----------------------
// 64x64 tiles through LDS; chunk-XOR swizzle g(d)=(d&7)^((d>>3)&7) keeps both
// the scalar-write and vector-read phases <=2-way bank conflicted.
__global__ __launch_bounds__(256) void transpose_v(const short* __restrict__ vb,
                                                   short* __restrict__ vt) {
  __shared__ char L[8192] __attribute__((aligned(128)));
  int bx = blockIdx.x;
  int bh = bx >> 6, rest = bx & 63, tt = rest >> 1, td = rest & 1;
  int t0 = tt * 64, d0 = td * 64;
  size_t base = (size_t)bh * (2048 * 128);
#pragma unroll
  for (int it = 0; it < 2; ++it) {
    int c = it * 256 + threadIdx.x;
    int t = c >> 3, dc = c & 7;
    bf16x8 v = *(const bf16x8*)(vb + base + (size_t)(t0 + t) * 128 + d0 + dc * 8);
#pragma unroll
    for (int i = 0; i < 8; ++i) {
      int d = dc * 8 + i;
      int g = (d & 7) ^ ((d >> 3) & 7);
      *(short*)(L + d * 128 + (((t >> 3) ^ g) * 16) + (t & 7) * 2) = v[i];
    }
  }
  __syncthreads();
#pragma unroll
  for (int it = 0; it < 2; ++it) {
    int c = it * 256 + threadIdx.x;
    int dr = c >> 3, tc = c & 7;
    int g = (dr & 7) ^ ((dr >> 3) & 7);
    bf16x8 v = *(const bf16x8*)(L + dr * 128 + ((tc ^ g) * 16));
    *(bf16x8*)(vt + base + (size_t)(d0 + dr) * 2048 + t0 + tc * 8) = v;
  }
}

// ------------------------------- GEMM (m97) --------------------------------
// C = A(M x K) * W(N x K)^T, bf16 in, 128x128 tile, BK=32, 4 waves 2x2.
// MODE 0: fused QKV, NT=48, writes bf16 to (B,H,T,D) buffers q/k/v.
// MODE 1: writes f32 row-major (final projection), NT=16.
template <int MODE>
__global__ __launch_bounds__(256) void gemm_bt(const short* __restrict__ A,
                                               const short* __restrict__ W0,
                                               const short* __restrict__ W1,
                                               const short* __restrict__ W2,
                                               short* __restrict__ oq,
                                               short* __restrict__ ok_,
                                               short* __restrict__ ov,
                                               float* __restrict__ of, int NT) {
  __shared__ char lds[16384] __attribute__((aligned(128)));
  int nwg = gridDim.x;
  int bid = blockIdx.x;
  int wg = (bid & 7) * (nwg >> 3) + (bid >> 3);   // XCD-chunked swizzle (nwg%8==0)
  int mt = wg / NT, nt = wg % NT;
  const int lane = threadIdx.x & 63;
  const int wid = threadIdx.x >> 6;
  const int wr = wid >> 1, wc = wid & 1;
  const int l15 = lane & 15, l4 = lane >> 4;
  const short* Wp;
  int n0, wsel = 0;
  if (MODE == 0) {
    wsel = nt >> 4;
    Wp = (wsel == 0) ? W0 : ((wsel == 1) ? W1 : W2);
    n0 = (nt & 15) * 128;
  } else {
    Wp = W0;
    n0 = nt * 128;
  }
  const int m0 = mt * 128;
  const f32x4 vzero = {0.f, 0.f, 0.f, 0.f};
  f32x4 acc[4][4];
#pragma unroll
  for (int i = 0; i < 4; ++i)
#pragma unroll
    for (int j = 0; j < 4; ++j) acc[i][j] = vzero;
  const short* Ab = A + (size_t)m0 * 2048;
  const short* Wb = Wp + (size_t)n0 * 2048;
  for (int k0 = 0; k0 < 2048; k0 += 32) {
#pragma unroll
    for (int j = 0; j < 2; ++j) {
      int c = j * 256 + (int)threadIdx.x;
      int row = c >> 2, slot = c & 3;
      int ldsoff = (c - lane) * 16;               // wave-uniform base
      gload_lds16(Ab + (size_t)row * 2048 + k0 + slot * 8, lds + ldsoff);
      gload_lds16(Wb + (size_t)row * 2048 + k0 + slot * 8, lds + 8192 + ldsoff);
    }
    __syncthreads();
    bf16x8 af[4], wf[4];
#pragma unroll
    for (int i = 0; i < 4; ++i) {
      af[i] = *(const bf16x8*)(lds + (wr * 64 + i * 16 + l15) * 64 + l4 * 16);
      wf[i] = *(const bf16x8*)(lds + 8192 + (wc * 64 + i * 16 + l15) * 64 + l4 * 16);
    }
#pragma unroll
    for (int i = 0; i < 4; ++i)
#pragma unroll
      for (int j = 0; j < 4; ++j)
        acc[i][j] = __builtin_amdgcn_mfma_f32_16x16x32_bf16(af[i], wf[j], acc[i][j], 0, 0, 0);
    __syncthreads();
  }
  // epilogue
#pragma unroll
  for (int mi = 0; mi < 4; ++mi) {
#pragma unroll
    for (int j = 0; j < 4; ++j) {
      int rr = m0 + wr * 64 + mi * 16 + l4 * 4 + j;
#pragma unroll
      for (int ni = 0; ni < 4; ++ni) {
        int cc = n0 + wc * 64 + ni * 16 + l15;
        float v = acc[mi][ni][j];
        if (MODE == 0) {
          int b = rr >> 11, t = rr & 2047, h = cc >> 7, d = cc & 127;
          short* o = (wsel == 0) ? oq : ((wsel == 1) ? ok_ : ov);
          o[(((size_t)b * 16 + h) * 2048 + t) * 128 + d] = f2bf(v);
        } else {
          of[(size_t)rr * 2048 + cc] = v;
        }
      }
    }
  }
}

// ------------------------------ flash attention ----------------------------
// 4 waves x 16 q-rows (BQ=64), KV tiles of 64, causal; block handles qtiles
// {p, 31-p} for perfect balance. K lds [64][128] / Vt lds [128][64] with
// byte ^= ((row&7)<<4) swizzle applied via pre-swizzled global_load_lds src.
__global__ __launch_bounds__(256) void attn_kernel(const short* __restrict__ qb,
                                                   const short* __restrict__ kb,
                                                   const short* __restrict__ vt,
                                                   short* __restrict__ aout) {
  __shared__ char lds[40960] __attribute__((aligned(128)));
  const int lane = threadIdx.x & 63;
  const int w = threadIdx.x >> 6;
  const int l15 = lane & 15, l4 = lane >> 4;
  int bid0 = blockIdx.x;
  int bid = (bid0 & 7) * 64 + (bid0 >> 3);        // keep each bh on one XCD
  const int bh = bid >> 4, p = bid & 15;
  const size_t qkbase = (size_t)bh * (2048 * 128); // also vt base (128*2048)
  char* Pb = lds + 32768 + w * 2048;
  const f32x4 vzero = {0.f, 0.f, 0.f, 0.f};

#pragma unroll 1
  for (int half = 0; half < 2; ++half) {
    const int qtile = half ? (31 - p) : p;
    const int qbase = qtile << 6;
    const int qrow = qbase + w * 16 + l15;
    bf16x8 aq[4];
#pragma unroll
    for (int ks = 0; ks < 4; ++ks)
      aq[ks] = *(const bf16x8*)(qb + qkbase + (size_t)qrow * 128 + ks * 32 + l4 * 8);
    f32x4 accO[8];
#pragma unroll
    for (int nt = 0; nt < 8; ++nt) accO[nt] = vzero;
    float m_[4], l_[4];
#pragma unroll
    for (int j = 0; j < 4; ++j) { m_[j] = -1e30f; l_[j] = 0.f; }

#pragma unroll 1
    for (int kt = 0; kt <= qtile; ++kt) {
      // ---- stage K tile and Vt tile (swizzled source, linear LDS dest) ----
#pragma unroll
      for (int j = 0; j < 4; ++j) {
        int c = j * 256 + (int)threadIdx.x;       // 0..1023
        int ldsoff = (c - lane) * 16;             // wave-uniform
        {
          int row = c >> 4, slot = c & 15;        // K: [64][128] bf16
          gload_lds16(kb + qkbase + (size_t)(kt * 64 + row) * 128 + ((slot ^ (row & 7)) * 8),
                      lds + ldsoff);
        }
        {
          int row = c >> 3, slot = c & 7;         // Vt: [128][64] bf16
          gload_lds16(vt + qkbase + (size_t)row * 2048 + kt * 64 + ((slot ^ (row & 7)) * 8),
                      lds + 16384 + ldsoff);
        }
      }
      __syncthreads();

      // ---- S = Q K^T (q pre-scaled by 1/sqrt(D)) ----
      f32x4 s[4];
#pragma unroll
      for (int ct = 0; ct < 4; ++ct) {
        s[ct] = vzero;
        int kcol = ct * 16 + l15;
#pragma unroll
        for (int ks = 0; ks < 4; ++ks) {
          bf16x8 bk = *(const bf16x8*)(lds + kcol * 256 + ((ks * 64 + l4 * 16) ^ ((kcol & 7) << 4)));
          s[ct] = __builtin_amdgcn_mfma_f32_16x16x32_bf16(aq[ks], bk, s[ct], 0, 0, 0);
        }
      }
      // ---- causal mask (only on the diagonal tile) ----
      if (kt * 64 + 63 > qbase + w * 16) {
#pragma unroll
        for (int ct = 0; ct < 4; ++ct) {
          int kc = kt * 64 + ct * 16 + l15;
#pragma unroll
          for (int j = 0; j < 4; ++j) {
            int r = qbase + w * 16 + l4 * 4 + j;
            if (kc > r) s[ct][j] = -1e30f;
          }
        }
      }
      // ---- online softmax (row groups of 16 lanes) ----
#pragma unroll
      for (int j = 0; j < 4; ++j) {
        float mx = fmaxf(fmaxf(s[0][j], s[1][j]), fmaxf(s[2][j], s[3][j]));
        mx = fmaxf(mx, __shfl_xor(mx, 1));
        mx = fmaxf(mx, __shfl_xor(mx, 2));
        mx = fmaxf(mx, __shfl_xor(mx, 4));
        mx = fmaxf(mx, __shfl_xor(mx, 8));
        float mn = fmaxf(m_[j], mx);
        float resc = __expf(m_[j] - mn);
        m_[j] = mn;
        float rs = 0.f;
#pragma unroll
        for (int ct = 0; ct < 4; ++ct) {
          float e = __expf(s[ct][j] - mn);
          s[ct][j] = e;
          rs += e;
        }
        rs += __shfl_xor(rs, 1);
        rs += __shfl_xor(rs, 2);
        rs += __shfl_xor(rs, 4);
        rs += __shfl_xor(rs, 8);
        l_[j] = l_[j] * resc + rs;
#pragma unroll
        for (int nt = 0; nt < 8; ++nt) accO[nt][j] *= resc;
      }
      // ---- P (C-layout) -> per-wave LDS (A-layout source), swizzled ----
#pragma unroll
      for (int ct = 0; ct < 4; ++ct)
#pragma unroll
        for (int j = 0; j < 4; ++j) {
          int r = l4 * 4 + j, cc = ct * 16 + l15;
          *(short*)(Pb + r * 128 + ((cc * 2) ^ ((r & 7) << 4))) = f2bf(s[ct][j]);
        }
      __threadfence_block();
      // ---- O += P V ----
#pragma unroll
      for (int ks2 = 0; ks2 < 2; ++ks2) {
        bf16x8 pa = *(const bf16x8*)(Pb + l15 * 128 + ((ks2 * 64 + l4 * 16) ^ ((l15 & 7) << 4)));
#pragma unroll
        for (int nt = 0; nt < 8; ++nt) {
          int d = nt * 16 + l15;
          bf16x8 bv = *(const bf16x8*)(lds + 16384 + d * 128 + ((ks2 * 64 + l4 * 16) ^ ((d & 7) << 4)));
          accO[nt] = __builtin_amdgcn_mfma_f32_16x16x32_bf16(pa, bv, accO[nt], 0, 0, 0);
        }
      }
      __syncthreads();
    }
    // ---- epilogue: normalize and write (B,T,C) bf16 ----
    const int b = bh >> 4, h = bh & 15;
#pragma unroll
    for (int j = 0; j < 4; ++j) {
      float inv = 1.0f / l_[j];
      int t = qbase + w * 16 + l4 * 4 + j;
      size_t obase = ((size_t)(b * 2048 + t)) * 2048 + h * 128;
#pragma unroll
      for (int nt = 0; nt < 8; ++nt)
        aout[obase + nt * 16 + l15] = f2bf(accO[nt][j] * inv);
    }
  }
}

// ------------------------------- launcher ----------------------------------
extern "C" void kernel_launch(void* const* d_in, const int* in_sizes, int n_in,
                              void* d_out, int out_size, void* d_ws, size_t ws_size,
                              hipStream_t stream) {
  const float* x  = (const float*)d_in[0];
  const float* fc = (const float*)d_in[1];
  const float* fs = (const float*)d_in[2];
  const float* wq = (const float*)d_in[3];
  const float* wk = (const float*)d_in[4];
  const float* wv = (const float*)d_in[5];
  const float* wo = (const float*)d_in[6];

  short* ws  = (short*)d_ws;
  short* xb  = ws;                    // 8388608 elems (x bf16) ; later reused as vt
  short* wqb = ws + 8388608;          // 4x 4194304 (weights bf16, consecutive)
  short* wkb = ws + 12582912;
  short* wvb = ws + 16777216;
  short* wob = ws + 20971520;
  short* qb  = ws + 25165824;         // (B,H,T,D) bf16
  short* kb  = ws + 33554432;
  short* vb  = ws + 41943040;         // later reused as aout
  short* vt  = xb;
  short* aout = vb;

  cast8_kernel<<<4096, 256, 0, stream>>>(x, xb, 1048576);
  castw_kernel<<<dim3(2048, 4), 256, 0, stream>>>(wq, wk, wv, wo, wqb);
  gemm_bt<0><<<1536, 256, 0, stream>>>(xb, wqb, wkb, wvb, qb, kb, vb, nullptr, 48);
  rope_kernel<<<4096, 256, 0, stream>>>(qb, fc, fs, 0.08838834764831845f); // 1/sqrt(128)
  rope_kernel<<<4096, 256, 0, stream>>>(kb, fc, fs, 1.0f);
  transpose_v<<<2048, 256, 0, stream>>>(vb, vt);
  attn_kernel<<<512, 256, 0, stream>>>(qb, kb, vt, aout);
  gemm_bt<1><<<512, 256, 0, stream>>>(aout, wob, nullptr, nullptr,
                                      nullptr, nullptr, nullptr, (float*)d_out, 16);
}